// Round 7
// baseline (2515.939 us; speedup 1.0000x reference)
//
#include <hip/hip_runtime.h>

#define NB 16
#define NC 256
#define NH 64
#define NW 64
#define NK 1024
#define HW (NH * NW)          // 4096
#define NPOS (NB * HW)        // 65536
#define NOUT (NB * NC * HW)   // 16777216

__device__ __forceinline__ float sq_rn(float x) { return __fmul_rn(x, x); }

// Exact replica of numpy pairwise_sum for sum(a*a) over n=256 (verified R2/R4/R6).
__device__ __forceinline__ float pairwise_sumsq_256(const float* __restrict__ a,
                                                    int stride) {
    float s_half[2];
#pragma unroll
    for (int h = 0; h < 2; ++h) {
        const float* base = a + (size_t)(h * 128) * stride;
        float r[8];
#pragma unroll
        for (int j = 0; j < 8; ++j) r[j] = sq_rn(base[(size_t)j * stride]);
        for (int i = 8; i < 128; i += 8) {
#pragma unroll
            for (int j = 0; j < 8; ++j)
                r[j] = __fadd_rn(r[j], sq_rn(base[(size_t)(i + j) * stride]));
        }
        s_half[h] = __fadd_rn(
            __fadd_rn(__fadd_rn(r[0], r[1]), __fadd_rn(r[2], r[3])),
            __fadd_rn(__fadd_rn(r[4], r[5]), __fadd_rn(r[6], r[7])));
    }
    return __fadd_rn(s_half[0], s_half[1]);
}

// ---------------------------------------------------------------------------
// Kernel A: cnorm[k] = numpy-fp32 sum(codebook[k]^2)
// ---------------------------------------------------------------------------
__global__ __launch_bounds__(256) void cnorm_kernel(const float* __restrict__ cb,
                                                    float* __restrict__ cnorm) {
    int k = blockIdx.x * 256 + threadIdx.x;
    if (k < NK) {
        cnorm[k] = pairwise_sumsq_256(cb + (size_t)k * NC, 1);
    }
}

// ---------------------------------------------------------------------------
// Kernel B (R7): single-pass 8x16 register-tiled fp32 GEMM argmin.
// Block: 512 thr = 8 waves, 64 positions, ALL 1024 codes in one pass.
// z_lds[256][64] (64 KB, staged once). cb double-buffered 8-d slices
// [2][8][1024] (64 KB) -> ONE barrier per slice (32 total; dbl-buffer makes
// write(s+1)/compute(s) overlap safe). 1 block/CU = 2 waves/SIMD.
// Thread grid: pg = t&7 (8 positions pg*8+i), cgl = t>>3 (codes
// k = r*256 + cgl*4 + j, r<4, j<4 -> 16-B-spaced lane addresses =
// conflict-free bank quads). acc[8][16] = 128 VGPRs.
// Bit-exact: acc = one sequential __fmaf_rn chain over ascending d;
// score = fl(fl(znorm+cnorm)-2*dot); idx tie-break in all cross-lane reduces.
// ---------------------------------------------------------------------------
__global__ __launch_bounds__(512, 2) void argmin_kernel(const float* __restrict__ z,
                                                        const float* __restrict__ cb,
                                                        const float* __restrict__ cnorm,
                                                        int* __restrict__ idx_ws,
                                                        float* __restrict__ idx_out) {
    __shared__ float z_lds[256][64];       // 65536 B, [d][p]
    __shared__ float cb_lds[2][8][1024];   // 65536 B, [buf][dl][code]
    __shared__ float znorm_s[64];          //   256 B
    __shared__ float red_v[8][64];         //  2048 B
    __shared__ int   red_i[8][64];         //  2048 B  -> 135424 B total

    const int blk = blockIdx.x;            // 0..1023
    const int b = blk >> 6;
    const int hw0 = (blk & 63) * 64;
    const int t = threadIdx.x;
    const int lane = t & 63;
    const int wave = t >> 6;               // 0..7
    const int pg = t & 7;                  // position group (8 pos)
    const int cg4 = (t >> 3) * 4;          // code base within each 256-run

    const float* zg = z + (size_t)b * (NC * HW) + hw0;

    // ---- stage z d-major (coalesced; <=2-way LDS banks)
#pragma unroll
    for (int i = 0; i < 8; ++i) {
        const int flat4 = i * 2048 + t * 4;
        const int d = flat4 >> 6;
        const int p = flat4 & 63;
        *(float4*)&z_lds[d][p] = *(const float4*)(zg + (size_t)d * HW + p);
    }
    // numpy-exact znorm (verified code path)
    if (wave == 0) znorm_s[lane] = pairwise_sumsq_256(zg + lane, HW);
    __syncthreads();

    float zn[8];
#pragma unroll
    for (int i = 0; i < 8; ++i) zn[i] = znorm_s[pg * 8 + i];

    float acc[8][16];
#pragma unroll
    for (int i = 0; i < 8; ++i)
#pragma unroll
        for (int u = 0; u < 16; ++u) acc[i][u] = 0.f;

    // staging: thread stages codes t and t+512 (column = code id)
    const float* cbg1 = cb + (size_t)t * NC;
    const float* cbg2 = cb + (size_t)(t + 512) * NC;
    float4 pa0 = *(const float4*)(cbg1);
    float4 pa1 = *(const float4*)(cbg1 + 4);
    float4 pb0 = *(const float4*)(cbg2);
    float4 pb1 = *(const float4*)(cbg2 + 4);

#pragma unroll 1
    for (int s = 0; s < 32; ++s) {
        float(*buf)[1024] = cb_lds[s & 1];
        buf[0][t] = pa0.x; buf[1][t] = pa0.y; buf[2][t] = pa0.z; buf[3][t] = pa0.w;
        buf[4][t] = pa1.x; buf[5][t] = pa1.y; buf[6][t] = pa1.z; buf[7][t] = pa1.w;
        buf[0][t + 512] = pb0.x; buf[1][t + 512] = pb0.y;
        buf[2][t + 512] = pb0.z; buf[3][t + 512] = pb0.w;
        buf[4][t + 512] = pb1.x; buf[5][t + 512] = pb1.y;
        buf[6][t + 512] = pb1.z; buf[7][t + 512] = pb1.w;
        __syncthreads();
        if (s < 31) {
            pa0 = *(const float4*)(cbg1 + (s + 1) * 8);
            pa1 = *(const float4*)(cbg1 + (s + 1) * 8 + 4);
            pb0 = *(const float4*)(cbg2 + (s + 1) * 8);
            pb1 = *(const float4*)(cbg2 + (s + 1) * 8 + 4);
        }
        const int ds = s * 8;
#pragma unroll
        for (int dl = 0; dl < 8; ++dl) {
            const int d = ds + dl;
            const float4 za = *(const float4*)&z_lds[d][pg * 8];
            const float4 zb = *(const float4*)&z_lds[d][pg * 8 + 4];
            const float zf[8] = {za.x, za.y, za.z, za.w, zb.x, zb.y, zb.z, zb.w};
#pragma unroll
            for (int r = 0; r < 4; ++r) {
                const float4 cv = *(const float4*)&buf[dl][r * 256 + cg4];
                const float cf[4] = {cv.x, cv.y, cv.z, cv.w};
#pragma unroll
                for (int j = 0; j < 4; ++j)
#pragma unroll
                    for (int i = 0; i < 8; ++i)
                        acc[i][r * 4 + j] =
                            __fmaf_rn(zf[i], cf[j], acc[i][r * 4 + j]);
            }
        }
    }

    // ---- scores; within-thread k ascending over (r,j) -> strict < ok
    float best[8];
    int bid[8];
#pragma unroll
    for (int i = 0; i < 8; ++i) { best[i] = 3.4e38f; bid[i] = 0; }
#pragma unroll
    for (int r = 0; r < 4; ++r) {
        const int k0 = r * 256 + cg4;
        const float4 cn = *(const float4*)(cnorm + k0);
        const float cnf[4] = {cn.x, cn.y, cn.z, cn.w};
#pragma unroll
        for (int j = 0; j < 4; ++j) {
            const int k = k0 + j;
#pragma unroll
            for (int i = 0; i < 8; ++i) {
                const float sc = __fsub_rn(__fadd_rn(zn[i], cnf[j]),
                                           __fmul_rn(2.0f, acc[i][r * 4 + j]));
                if (sc < best[i]) { best[i] = sc; bid[i] = k; }
            }
        }
    }

    // ---- reduce across cgl within wave (k-ranges interleave -> idx tie-break)
#pragma unroll
    for (int off = 32; off >= 8; off >>= 1) {
#pragma unroll
        for (int i = 0; i < 8; ++i) {
            const float v = __shfl_down(best[i], off, 64);
            const int d2 = __shfl_down(bid[i], off, 64);
            if (v < best[i] || (v == best[i] && d2 < bid[i])) {
                best[i] = v;
                bid[i] = d2;
            }
        }
    }
    if ((lane >> 3) == 0) {                // lanes 0..7: pg = lane
#pragma unroll
        for (int i = 0; i < 8; ++i) {
            red_v[wave][pg * 8 + i] = best[i];
            red_i[wave][pg * 8 + i] = bid[i];
        }
    }
    __syncthreads();

    // ---- final reduce across 8 waves (interleaved k -> idx tie-break)
    if (t < 64) {
        float bv = red_v[0][t];
        int bi = red_i[0][t];
#pragma unroll
        for (int w = 1; w < 8; ++w) {
            const float v = red_v[w][t];
            const int i2 = red_i[w][t];
            if (v < bv || (v == bv && i2 < bi)) { bv = v; bi = i2; }
        }
        const int g = b * HW + hw0 + t;
        idx_ws[g] = bi;
        idx_out[g] = (float)bi;
    }
}

// ---------------------------------------------------------------------------
// Kernel C (R7): gather via ONE float4 row-gather per 4 outputs.
// Block = (b,h); thread: w = t&63 (idx in register), c-group = t>>6.
// Per iter: cb[idx_w][c4..c4+3] (16B gather, same row) -> 4 coalesced b32
// stores to out[b][c4+j][h][w] + 4 coalesced b32 z loads for the loss.
// ---------------------------------------------------------------------------
__global__ __launch_bounds__(256) void gather_loss_kernel(const float* __restrict__ z,
                                                          const float* __restrict__ cb,
                                                          const int* __restrict__ idx_ws,
                                                          float* __restrict__ out,
                                                          double* __restrict__ loss_acc) {
    const int blk = blockIdx.x;           // 0..1023
    const int b = blk >> 6;
    const int h = blk & 63;
    const int t = threadIdx.x;
    const int w = t & 63;
    const int cgrp = t >> 6;              // 0..3

    const int p = b * HW + h * NW + w;
    const int idx_w = idx_ws[p];
    const float* cbrow = cb + (size_t)idx_w * NC;

    const size_t ebase = (size_t)b * (NC * HW) + (size_t)h * NW + w;

    float part = 0.f;
#pragma unroll 2
    for (int it = 0; it < 16; ++it) {
        const int c4 = it * 16 + cgrp * 4;
        const float4 cv = *(const float4*)(cbrow + c4);
        const float cf[4] = {cv.x, cv.y, cv.z, cv.w};
#pragma unroll
        for (int j = 0; j < 4; ++j) {
            const size_t e = ebase + (size_t)(c4 + j) * HW;
            const float zv = z[e];
            out[e] = cf[j];
            const float d = cf[j] - zv;
            part = fmaf(d, d, part);
        }
    }

#pragma unroll
    for (int off = 32; off > 0; off >>= 1) part += __shfl_down(part, off, 64);

    __shared__ float wsum[4];
    const int lane = t & 63;
    const int wave = t >> 6;
    if (lane == 0) wsum[wave] = part;
    __syncthreads();
    if (t == 0) {
        float s = wsum[0] + wsum[1] + wsum[2] + wsum[3];
        atomicAdd(loss_acc, (double)s);
    }
}

// ---------------------------------------------------------------------------
// Kernel D: loss = (1 + beta) * sum / NOUT
// ---------------------------------------------------------------------------
__global__ void finalize_kernel(const double* __restrict__ loss_acc,
                                float* __restrict__ out_loss) {
    if (threadIdx.x == 0) {
        *out_loss = (float)(1.25 * (*loss_acc) / (double)NOUT);
    }
}

extern "C" void kernel_launch(void* const* d_in, const int* in_sizes, int n_in,
                              void* d_out, int out_size, void* d_ws, size_t ws_size,
                              hipStream_t stream) {
    const float* z = (const float*)d_in[0];
    const float* cb = (const float*)d_in[1];

    float* out = (float*)d_out;            // [16,256,64,64]
    float* loss_out = out + NOUT;          // scalar
    float* idx_out = out + NOUT + 1;       // [16,1,64,64] as float

    double* loss_acc = (double*)d_ws;                      // 8 B (zeroed below)
    float* cnorm = (float*)((char*)d_ws + 64);             // 4 KB
    int* idx_ws = (int*)((char*)d_ws + 64 + NK * 4);       // 256 KB

    hipMemsetAsync(d_ws, 0, 64, stream);
    cnorm_kernel<<<(NK + 255) / 256, 256, 0, stream>>>(cb, cnorm);
    argmin_kernel<<<NPOS / 64, 512, 0, stream>>>(z, cb, cnorm, idx_ws, idx_out);
    gather_loss_kernel<<<NB * NH, 256, 0, stream>>>(z, cb, idx_ws, out, loss_acc);
    finalize_kernel<<<1, 64, 0, stream>>>(loss_acc, loss_out);
}